// Round 3
// baseline (1168.952 us; speedup 1.0000x reference)
//
#include <hip/hip_runtime.h>
#include <stdint.h>
#include <math.h>

#define BT   65536
#define H    4
#define K    512
#define DH   256
#define EPSN 1e-12f
#define EPSL 1e-10f
#define TAU  0.03f
#define CMAX 16
#define NREP 8            // avg_probs accumulator replicas

typedef short bf16x8 __attribute__((ext_vector_type(8)));
typedef float f32x4  __attribute__((ext_vector_type(4)));

__device__ inline unsigned short f2bf(float f) {
  uint32_t u = __builtin_bit_cast(uint32_t, f);
  u += 0x7fffu + ((u >> 16) & 1u);
  return (unsigned short)(u >> 16);
}

// ---------------------------------------------------------------------------
// ws layout (float slots):
//   en_f  : [H][K][DH] fp32 normalized      524288 floats
//   en_b  : [H][K][DH] bf16 normalized      131072 float slots
//   avgp  : [NREP][H*K]                     16384 floats
//   idx_ws: [BT][H] int                     262144
// ---------------------------------------------------------------------------

__global__ __launch_bounds__(256) void vq_prep(const float* __restrict__ emb,
                                               float* __restrict__ en_f,
                                               unsigned short* __restrict__ en_b,
                                               float* __restrict__ avgp) {
  const int hk = blockIdx.x;        // h*K + k
  const int t  = threadIdx.x;       // d
  const float v = emb[(size_t)hk * DH + t];
  float s = v * v;
#pragma unroll
  for (int m = 1; m < 64; m <<= 1) s += __shfl_xor(s, m);
  __shared__ float wsum[4];
  if ((t & 63) == 0) wsum[t >> 6] = s;
  __syncthreads();
  const float tot = wsum[0] + wsum[1] + wsum[2] + wsum[3];
  const float n   = fmaxf(sqrtf(tot), EPSN);
  const float vn  = v / n;
  en_f[(size_t)hk * DH + t] = vn;
  en_b[(size_t)hk * DH + t] = f2bf(vn);
  if (t < NREP) avgp[t * (H * K) + hk] = 0.0f;
}

// Block: 64 b-rows x all 512 codes for one h. 256 threads = 4 waves.
// Wave w owns cols [128w, 128w+128): 4 (mi) x 8 (ni) 16x16 frags, K=256 in 8 steps.
__global__ __launch_bounds__(256, 4) void vq_main(
    const float* __restrict__ z_e, const float* __restrict__ emb,
    const float* __restrict__ scales,
    const float* __restrict__ en_f, const unsigned short* __restrict__ en_b,
    float* __restrict__ avgp, int* __restrict__ idx_ws,
    float* __restrict__ outq) {
  const int h     = blockIdx.y;
  const int bbase = blockIdx.x * 64;
  const int t     = threadIdx.x;
  const int w     = t >> 6;
  const int l     = t & 63;

  __shared__ unsigned short a_lds[64 * 256];     // 32 KiB, XOR-swizzled bf16
  __shared__ float norms[64];
  __shared__ float wred[4][64];                  // per-wave maxes, then exp-sums
  __shared__ int   wcols[4][64];
  __shared__ unsigned short cand[64][CMAX];      // 2 KiB
  __shared__ float gmx[64];
  __shared__ int   gcol[64];
  __shared__ float Srec[64];
  __shared__ int   cnt[64];
  __shared__ int   fidx[64];
  // total LDS = 32768+256+1024+1024+2048+256+256+256+256+256 = 38400 B -> 4 blk/CU

  // ---- stage A: load z row, L2-normalize (ref: x / max(sqrt(ss),eps)), bf16->LDS ----
  {
    const int row = (w << 4) | (l >> 2);         // 0..63
    const int c4  = l & 3;
    const float* zp = z_e + (size_t)(bbase + row) * (H * DH) + h * DH;
    float4 q[16];
    float ss = 0.0f;
#pragma unroll
    for (int j = 0; j < 16; j++) {
      q[j] = *(const float4*)(zp + c4 * 4 + j * 16);
      ss += q[j].x * q[j].x + q[j].y * q[j].y + q[j].z * q[j].z + q[j].w * q[j].w;
    }
    ss += __shfl_xor(ss, 1);
    ss += __shfl_xor(ss, 2);
    const float n   = fmaxf(sqrtf(ss), EPSN);
    const float inv = 1.0f / n;
    if (c4 == 0) norms[row] = n;
    const int swz = (row & 7) << 4;
#pragma unroll
    for (int j = 0; j < 16; j++) {
      const int d = c4 * 4 + j * 16;
      uint2 pk;
      pk.x = (uint32_t)f2bf(q[j].x * inv) | ((uint32_t)f2bf(q[j].y * inv) << 16);
      pk.y = (uint32_t)f2bf(q[j].z * inv) | ((uint32_t)f2bf(q[j].w * inv) << 16);
      *(uint2*)((char*)a_lds + row * 512 + ((d * 2) ^ swz)) = pk;
    }
    if (t < 64) cnt[t] = 0;
  }
  __syncthreads();

  // ---- MFMA GEMM ----
  f32x4 acc[4][8];
#pragma unroll
  for (int mi = 0; mi < 4; mi++)
#pragma unroll
    for (int ni = 0; ni < 8; ni++) acc[mi][ni] = (f32x4){0.f, 0.f, 0.f, 0.f};

  const int arow = l & 15;
  const int kg   = l >> 4;                       // 0..3
  const int aswz = (arow & 7) << 4;
  const unsigned short* bp =
      en_b + ((size_t)(h * K) + w * 128 + arow) * DH + kg * 8;

#pragma unroll
  for (int ks = 0; ks < 8; ks++) {
    bf16x8 af[4];
#pragma unroll
    for (int mi = 0; mi < 4; mi++) {
      const int row = (mi << 4) | arow;
      const int kb  = (ks * 64) | (kg * 16);
      af[mi] = *(const bf16x8*)((const char*)a_lds + row * 512 + (kb ^ aswz));
    }
    bf16x8 bfr[8];
#pragma unroll
    for (int ni = 0; ni < 8; ni++)
      bfr[ni] = *(const bf16x8*)(bp + (size_t)ni * 16 * DH + ks * 32);
#pragma unroll
    for (int mi = 0; mi < 4; mi++)
#pragma unroll
      for (int ni = 0; ni < 8; ni++)
        acc[mi][ni] = __builtin_amdgcn_mfma_f32_16x16x32_bf16(af[mi], bfr[ni],
                                                              acc[mi][ni], 0, 0, 0);
  }

  const float sc = scales[h];
#pragma unroll
  for (int mi = 0; mi < 4; mi++)
#pragma unroll
    for (int ni = 0; ni < 8; ni++)
#pragma unroll
      for (int q = 0; q < 4; q++) acc[mi][ni][q] *= sc;

  // C layout: col = 128w + 16ni + (l&15), row = 16mi + 4*(l>>4) + q
  // ---- per-row max over this wave's 128 cols ----
  float tmx[4][4]; int tcol[4][4];
#pragma unroll
  for (int mi = 0; mi < 4; mi++)
#pragma unroll
    for (int q = 0; q < 4; q++) { tmx[mi][q] = -INFINITY; tcol[mi][q] = 1 << 30; }
#pragma unroll
  for (int mi = 0; mi < 4; mi++)
#pragma unroll
    for (int ni = 0; ni < 8; ni++) {
      const int col = w * 128 + ni * 16 + arow;
#pragma unroll
      for (int q = 0; q < 4; q++) {
        const float v = acc[mi][ni][q];
        if (v > tmx[mi][q]) { tmx[mi][q] = v; tcol[mi][q] = col; }
      }
    }
#pragma unroll
  for (int m = 1; m < 16; m <<= 1) {
#pragma unroll
    for (int mi = 0; mi < 4; mi++)
#pragma unroll
      for (int q = 0; q < 4; q++) {
        const float om = __shfl_xor(tmx[mi][q], m);
        const int   oc = __shfl_xor(tcol[mi][q], m);
        if (om > tmx[mi][q] || (om == tmx[mi][q] && oc < tcol[mi][q])) {
          tmx[mi][q] = om; tcol[mi][q] = oc;
        }
      }
  }
  if (arow == 0) {
#pragma unroll
    for (int mi = 0; mi < 4; mi++)
#pragma unroll
      for (int q = 0; q < 4; q++) {
        const int row = 16 * mi + 4 * kg + q;
        wred[w][row]  = tmx[mi][q];
        wcols[w][row] = tcol[mi][q];
      }
  }
  __syncthreads();
  if (t < 64) {
    float m = -INFINITY; int c = 1 << 30;
#pragma unroll
    for (int ww = 0; ww < 4; ww++) {
      const float vm = wred[ww][t];
      const int   vc = wcols[ww][t];
      if (vm > m || (vm == m && vc < c)) { m = vm; c = vc; }
    }
    gmx[t] = m; gcol[t] = c;
  }
  __syncthreads();

  // ---- candidate scan: approx logit >= gmax - TAU ----
#pragma unroll
  for (int mi = 0; mi < 4; mi++)
#pragma unroll
    for (int ni = 0; ni < 8; ni++) {
      const int col = w * 128 + ni * 16 + arow;
#pragma unroll
      for (int q = 0; q < 4; q++) {
        const int row = 16 * mi + 4 * kg + q;
        if (acc[mi][ni][q] >= gmx[row] - TAU) {
          const int p = atomicAdd(&cnt[row], 1);
          if (p < CMAX) cand[row][p] = (unsigned short)col;
        }
      }
    }
  __syncthreads();

  // ---- refine: exact fp32 dot for multi-candidate rows (64-lane cooperative) ----
  for (int r = w; r < 64; r += 4) {
    int c = cnt[r];
    int best;
    if (c <= 1) {
      best = gcol[r];
    } else {
      if (c > CMAX) c = CMAX;
      const float nrm = norms[r];
      const float4 zq = *(const float4*)(z_e + (size_t)(bbase + r) * (H * DH) +
                                         h * DH + l * 4);
      const float zn0 = zq.x / nrm, zn1 = zq.y / nrm,
                  zn2 = zq.z / nrm, zn3 = zq.w / nrm;
      float bv = -INFINITY; int bi = 1 << 30;
      for (int i = 0; i < c; i++) {
        const int cc = cand[r][i];
        const float4 eq = *(const float4*)(en_f + ((size_t)(h * K) + cc) * DH + l * 4);
        float d0 = fmaf(zn0, eq.x, fmaf(zn1, eq.y, fmaf(zn2, eq.z, zn3 * eq.w)));
#pragma unroll
        for (int m = 1; m < 64; m <<= 1) d0 += __shfl_xor(d0, m);
        const float val = sc * d0;
        if (val > bv || (val == bv && cc < bi)) { bv = val; bi = cc; }
      }
      best = bi;
    }
    if (l == 0) fidx[r] = best;
  }

  // ---- exp in place + per-row sums (|logit|<=~10: no max shift needed) ----
  float tsum[4][4];
#pragma unroll
  for (int mi = 0; mi < 4; mi++)
#pragma unroll
    for (int q = 0; q < 4; q++) tsum[mi][q] = 0.0f;
#pragma unroll
  for (int mi = 0; mi < 4; mi++)
#pragma unroll
    for (int ni = 0; ni < 8; ni++)
#pragma unroll
      for (int q = 0; q < 4; q++) {
        const float e = __expf(acc[mi][ni][q]);
        acc[mi][ni][q] = e;
        tsum[mi][q] += e;
      }
#pragma unroll
  for (int m = 1; m < 16; m <<= 1)
#pragma unroll
    for (int mi = 0; mi < 4; mi++)
#pragma unroll
      for (int q = 0; q < 4; q++) tsum[mi][q] += __shfl_xor(tsum[mi][q], m);
  if (arow == 0) {
#pragma unroll
    for (int mi = 0; mi < 4; mi++)
#pragma unroll
      for (int q = 0; q < 4; q++) wred[w][16 * mi + 4 * kg + q] = tsum[mi][q];
  }
  __syncthreads();
  if (t < 64)
    Srec[t] = 1.0f / (wred[0][t] + wred[1][t] + wred[2][t] + wred[3][t]);
  __syncthreads();

  // ---- avg_probs partial via reciprocal + fma; one atomic per col per block ----
  {
    float vcol[8];
#pragma unroll
    for (int ni = 0; ni < 8; ni++) vcol[ni] = 0.0f;
#pragma unroll
    for (int mi = 0; mi < 4; mi++)
#pragma unroll
      for (int q = 0; q < 4; q++) {
        const float rs = Srec[16 * mi + 4 * kg + q];
#pragma unroll
        for (int ni = 0; ni < 8; ni++)
          vcol[ni] = fmaf(acc[mi][ni][q], rs, vcol[ni]);
      }
    float* ap = avgp + (blockIdx.x & (NREP - 1)) * (H * K) + h * K;
#pragma unroll
    for (int ni = 0; ni < 8; ni++) {
      float v = vcol[ni];
      v += __shfl_xor(v, 16);
      v += __shfl_xor(v, 32);
      if (l < 16) atomicAdd(&ap[w * 128 + ni * 16 + arow], v);
    }
  }
  if (t < 64) idx_ws[(size_t)(bbase + t) * H + h] = fidx[t];

  // ---- fused z_q gather: raw emb rows, coalesced 1 KiB per row ----
#pragma unroll 2
  for (int i = 0; i < 16; i++) {
    const int row = (w << 4) | i;
    const int idx = fidx[row];
    const float4 v = *(const float4*)(emb + ((size_t)(h * K) + idx) * DH + l * 4);
    *(float4*)(outq + (size_t)(bbase + row) * (H * DH) + h * DH + l * 4) = v;
  }
}

// combined = ((idx0*512 + idx1)*512 + idx2)*512 + idx3 with int32 wraparound.
__global__ __launch_bounds__(256) void vq_combined(const int* __restrict__ idx_ws,
                                                   float* __restrict__ out_comb) {
  const int b = blockIdx.x * 256 + threadIdx.x;
  if (b < BT) {
    const int* p = idx_ws + (size_t)b * H;
    uint32_t cv = (uint32_t)p[0];
    cv = cv * 512u + (uint32_t)p[1];
    cv = cv * 512u + (uint32_t)p[2];
    cv = cv * 512u + (uint32_t)p[3];
    out_comb[b] = (float)(int32_t)cv;
  }
}

__global__ __launch_bounds__(256) void vq_perp(const float* __restrict__ avgp,
                                               float* __restrict__ out_perp) {
  const int t = threadIdx.x;
  float sh[H] = {0.f, 0.f, 0.f, 0.f};
  for (int i = t; i < H * K; i += 256) {
    const int h = i >> 9;
    float a = 0.0f;
#pragma unroll
    for (int c = 0; c < NREP; c++) a += avgp[c * (H * K) + i];
    a /= 65536.0f;
    sh[h] += a * logf(a + EPSL);
  }
  __shared__ float red[4][H];
#pragma unroll
  for (int h = 0; h < H; h++) {
    float s = sh[h];
#pragma unroll
    for (int m = 1; m < 64; m <<= 1) s += __shfl_xor(s, m);
    if ((t & 63) == 0) red[t >> 6][h] = s;
  }
  __syncthreads();
  if (t == 0) {
    float p = 0.0f;
#pragma unroll
    for (int h = 0; h < H; h++) {
      const float s = red[0][h] + red[1][h] + red[2][h] + red[3][h];
      p += expf(-s);
    }
    out_perp[0] = p * 0.25f;
  }
}

extern "C" void kernel_launch(void* const* d_in, const int* in_sizes, int n_in,
                              void* d_out, int out_size, void* d_ws, size_t ws_size,
                              hipStream_t stream) {
  const float* z_e    = (const float*)d_in[0];
  const float* emb    = (const float*)d_in[1];
  const float* scales = (const float*)d_in[2];
  float* out = (float*)d_out;

  float*          en_f   = (float*)d_ws;                        // 524288 floats
  unsigned short* en_b   = (unsigned short*)(en_f + (size_t)H * K * DH);
  float*          avgp   = (float*)(en_b + (size_t)H * K * DH); // NREP*2048 floats
  int*            idx_ws = (int*)(avgp + NREP * H * K);         // 262144 ints

  hipLaunchKernelGGL(vq_prep, dim3(H * K), dim3(256), 0, stream,
                     emb, en_f, en_b, avgp);
  hipLaunchKernelGGL(vq_main, dim3(BT / 64, H), dim3(256), 0, stream,
                     z_e, emb, scales, en_f, en_b, avgp, idx_ws, out);
  hipLaunchKernelGGL(vq_combined, dim3(BT / 256), dim3(256), 0, stream,
                     idx_ws, out + (size_t)BT * H * DH);
  hipLaunchKernelGGL(vq_perp, dim3(1), dim3(256), 0, stream,
                     avgp, out + (size_t)BT * H * DH + BT);
}

// Round 4
// 359.280 us; speedup vs baseline: 3.2536x; 3.2536x over previous
//
#include <hip/hip_runtime.h>
#include <stdint.h>
#include <math.h>

#define BT   65536
#define H    4
#define K    512
#define DH   256
#define EPSN 1e-12f
#define EPSL 1e-10f
#define TAU  0.03f
#define CTH  0.970446f      // exp(-TAU)
#define CMAX 16
#define NREP 8              // avg_probs accumulator replicas

typedef short bf16x8 __attribute__((ext_vector_type(8)));
typedef float f32x4  __attribute__((ext_vector_type(4)));

__device__ inline unsigned short f2bf(float f) {
  uint32_t u = __builtin_bit_cast(uint32_t, f);
  u += 0x7fffu + ((u >> 16) & 1u);
  return (unsigned short)(u >> 16);
}

// ---------------------------------------------------------------------------
// ws layout (float slots):
//   en_f  : [H][K][DH] fp32 normalized      524288 floats
//   en_b  : [H][K][DH] bf16 normalized      131072 float slots
//   avgp  : [NREP][H*K]                     16384 floats
//   idx_ws: [BT][H] int                     262144
// ---------------------------------------------------------------------------

__global__ __launch_bounds__(256) void vq_prep(const float* __restrict__ emb,
                                               float* __restrict__ en_f,
                                               unsigned short* __restrict__ en_b,
                                               float* __restrict__ avgp) {
  const int hk = blockIdx.x;        // h*K + k
  const int t  = threadIdx.x;       // d
  const float v = emb[(size_t)hk * DH + t];
  float s = v * v;
#pragma unroll
  for (int m = 1; m < 64; m <<= 1) s += __shfl_xor(s, m);
  __shared__ float wsum[4];
  if ((t & 63) == 0) wsum[t >> 6] = s;
  __syncthreads();
  const float tot = wsum[0] + wsum[1] + wsum[2] + wsum[3];
  const float n   = fmaxf(sqrtf(tot), EPSN);
  const float vn  = v / n;
  en_f[(size_t)hk * DH + t] = vn;
  en_b[(size_t)hk * DH + t] = f2bf(vn);
  if (t < NREP) avgp[t * (H * K) + hk] = 0.0f;
}

// Block: 64 b-rows x all 512 codes for one h. 256 threads = 4 waves.
// Wave w owns cols [128w, 128w+128): 4 (mi) x 8 (ni) 16x16 frags, K=256 in 8 steps.
// NOTE: acc (128 f32/lane, AGPR) + ~120 VGPR => 2 waves/SIMD is the hard cap.
// launch_bounds(256,4) forces spills (round-3: 3 GB scratch traffic). Keep (256,2).
__global__ __launch_bounds__(256, 2) void vq_main(
    const float* __restrict__ z_e, const float* __restrict__ emb,
    const float* __restrict__ scales,
    const float* __restrict__ en_f, const unsigned short* __restrict__ en_b,
    float* __restrict__ avgp, int* __restrict__ idx_ws,
    float* __restrict__ outq) {
  const int h     = blockIdx.y;
  const int bbase = blockIdx.x * 64;
  const int t     = threadIdx.x;
  const int w     = t >> 6;
  const int l     = t & 63;

  __shared__ unsigned short a_lds[64 * 256];     // 32 KiB, XOR-swizzled bf16
  __shared__ float norms[64];
  __shared__ float wredm[4][64];                 // per-wave exp-maxes
  __shared__ float wreds[4][64];                 // per-wave exp-sums
  __shared__ int   wcols[4][64];
  __shared__ unsigned short cand[64][CMAX];
  __shared__ float gmx[64];                      // block exp-max
  __shared__ int   gcol[64];
  __shared__ float Srec[64];                     // 1/sum
  __shared__ int   cnt[64];
  __shared__ int   fidx[64];

  // ---- stage A: load z row, L2-normalize (ref semantics), bf16 -> LDS ----
  {
    const int row = (w << 4) | (l >> 2);         // 0..63
    const int c4  = l & 3;
    const float* zp = z_e + (size_t)(bbase + row) * (H * DH) + h * DH;
    float4 q[16];
    float ss = 0.0f;
#pragma unroll
    for (int j = 0; j < 16; j++) {
      q[j] = *(const float4*)(zp + c4 * 4 + j * 16);
      ss += q[j].x * q[j].x + q[j].y * q[j].y + q[j].z * q[j].z + q[j].w * q[j].w;
    }
    ss += __shfl_xor(ss, 1);
    ss += __shfl_xor(ss, 2);
    const float n   = fmaxf(sqrtf(ss), EPSN);
    const float inv = 1.0f / n;
    if (c4 == 0) norms[row] = n;
    const int swz = (row & 7) << 4;
#pragma unroll
    for (int j = 0; j < 16; j++) {
      const int d = c4 * 4 + j * 16;
      uint2 pk;
      pk.x = (uint32_t)f2bf(q[j].x * inv) | ((uint32_t)f2bf(q[j].y * inv) << 16);
      pk.y = (uint32_t)f2bf(q[j].z * inv) | ((uint32_t)f2bf(q[j].w * inv) << 16);
      *(uint2*)((char*)a_lds + row * 512 + ((d * 2) ^ swz)) = pk;
    }
    if (t < 64) cnt[t] = 0;
  }
  __syncthreads();

  // ---- MFMA GEMM ----
  f32x4 acc[4][8];
#pragma unroll
  for (int mi = 0; mi < 4; mi++)
#pragma unroll
    for (int ni = 0; ni < 8; ni++) acc[mi][ni] = (f32x4){0.f, 0.f, 0.f, 0.f};

  const int arow = l & 15;
  const int kg   = l >> 4;                       // 0..3
  const int aswz = (arow & 7) << 4;
  const unsigned short* bp =
      en_b + ((size_t)(h * K) + w * 128 + arow) * DH + kg * 8;

#pragma unroll
  for (int ks = 0; ks < 8; ks++) {
    bf16x8 af[4];
#pragma unroll
    for (int mi = 0; mi < 4; mi++) {
      const int row = (mi << 4) | arow;
      const int kb  = (ks * 64) | (kg * 16);
      af[mi] = *(const bf16x8*)((const char*)a_lds + row * 512 + (kb ^ aswz));
    }
    bf16x8 bfr[8];
#pragma unroll
    for (int ni = 0; ni < 8; ni++)
      bfr[ni] = *(const bf16x8*)(bp + (size_t)ni * 16 * DH + ks * 32);
#pragma unroll
    for (int mi = 0; mi < 4; mi++)
#pragma unroll
      for (int ni = 0; ni < 8; ni++)
        acc[mi][ni] = __builtin_amdgcn_mfma_f32_16x16x32_bf16(af[mi], bfr[ni],
                                                              acc[mi][ni], 0, 0, 0);
  }

  // C layout: col = 128w + 16ni + (l&15), row = 16mi + 4*(l>>4) + q
  // ---- fused pass 1: e = exp(sc*logit) in place; per-lane max/argmax/sum.
  // argmax in exp domain == argmax in logit domain (monotone); rounding
  // collapses only within-TAU pairs, which the refine path resolves exactly.
  const float sc = scales[h];
  float tm[4][4]; int tc[4][4]; float ts[4][4];
#pragma unroll
  for (int mi = 0; mi < 4; mi++)
#pragma unroll
    for (int q = 0; q < 4; q++) { tm[mi][q] = 0.0f; tc[mi][q] = 1 << 30; ts[mi][q] = 0.0f; }
#pragma unroll
  for (int mi = 0; mi < 4; mi++)
#pragma unroll
    for (int ni = 0; ni < 8; ni++) {
      const int col = w * 128 + ni * 16 + arow;
#pragma unroll
      for (int q = 0; q < 4; q++) {
        const float e = __expf(sc * acc[mi][ni][q]);
        acc[mi][ni][q] = e;
        if (e > tm[mi][q]) { tm[mi][q] = e; tc[mi][q] = col; }
        ts[mi][q] += e;
      }
    }
#pragma unroll
  for (int m = 1; m < 16; m <<= 1) {
#pragma unroll
    for (int mi = 0; mi < 4; mi++)
#pragma unroll
      for (int q = 0; q < 4; q++) {
        const float om = __shfl_xor(tm[mi][q], m);
        const int   oc = __shfl_xor(tc[mi][q], m);
        if (om > tm[mi][q] || (om == tm[mi][q] && oc < tc[mi][q])) {
          tm[mi][q] = om; tc[mi][q] = oc;
        }
        ts[mi][q] += __shfl_xor(ts[mi][q], m);
      }
  }
  if (arow == 0) {
#pragma unroll
    for (int mi = 0; mi < 4; mi++)
#pragma unroll
      for (int q = 0; q < 4; q++) {
        const int row = 16 * mi + 4 * kg + q;
        wredm[w][row] = tm[mi][q];
        wcols[w][row] = tc[mi][q];
        wreds[w][row] = ts[mi][q];
      }
  }
  __syncthreads();
  if (t < 64) {
    float m = 0.0f; int c = 1 << 30; float s = 0.0f;
#pragma unroll
    for (int ww = 0; ww < 4; ww++) {
      const float vm = wredm[ww][t];
      const int   vc = wcols[ww][t];
      if (vm > m || (vm == m && vc < c)) { m = vm; c = vc; }
      s += wreds[ww][t];
    }
    gmx[t] = m; gcol[t] = c; Srec[t] = 1.0f / s;
  }
  __syncthreads();

  // ---- fused pass 2: candidate scan (e >= gmax*exp(-TAU)) + avg_probs ----
  {
    float vcol[8];
#pragma unroll
    for (int ni = 0; ni < 8; ni++) vcol[ni] = 0.0f;
#pragma unroll
    for (int mi = 0; mi < 4; mi++)
#pragma unroll
      for (int q = 0; q < 4; q++) {
        const int row  = 16 * mi + 4 * kg + q;
        const float rs = Srec[row];
        const float th = gmx[row] * CTH;
#pragma unroll
        for (int ni = 0; ni < 8; ni++) {
          const float e = acc[mi][ni][q];
          vcol[ni] = fmaf(e, rs, vcol[ni]);
          if (e >= th) {
            const int p = atomicAdd(&cnt[row], 1);
            if (p < CMAX) cand[row][p] = (unsigned short)(w * 128 + ni * 16 + arow);
          }
        }
      }
    float* ap = avgp + (blockIdx.x & (NREP - 1)) * (H * K) + h * K;
#pragma unroll
    for (int ni = 0; ni < 8; ni++) {
      float v = vcol[ni];
      v += __shfl_xor(v, 16);
      v += __shfl_xor(v, 32);
      if (l < 16) atomicAdd(&ap[w * 128 + ni * 16 + arow], v);
    }
  }
  __syncthreads();

  // ---- refine: exact fp32 dot for multi-candidate rows (64-lane cooperative) ----
  for (int r = w; r < 64; r += 4) {
    int c = cnt[r];
    int best;
    if (c <= 1) {
      best = gcol[r];
    } else {
      if (c > CMAX) c = CMAX;
      const float nrm = norms[r];
      const float4 zq = *(const float4*)(z_e + (size_t)(bbase + r) * (H * DH) +
                                         h * DH + l * 4);
      const float zn0 = zq.x / nrm, zn1 = zq.y / nrm,
                  zn2 = zq.z / nrm, zn3 = zq.w / nrm;
      float bv = -INFINITY; int bi = 1 << 30;
      for (int i = 0; i < c; i++) {
        const int cc = cand[r][i];
        const float4 eq = *(const float4*)(en_f + ((size_t)(h * K) + cc) * DH + l * 4);
        float d0 = fmaf(zn0, eq.x, fmaf(zn1, eq.y, fmaf(zn2, eq.z, zn3 * eq.w)));
#pragma unroll
        for (int m = 1; m < 64; m <<= 1) d0 += __shfl_xor(d0, m);
        if (d0 > bv || (d0 == bv && cc < bi)) { bv = d0; bi = cc; }
      }
      best = bi;
    }
    if (l == 0) fidx[r] = best;
  }
  __syncthreads();

  if (t < 64) idx_ws[(size_t)(bbase + t) * H + h] = fidx[t];

  // ---- fused z_q gather: raw emb rows, coalesced 1 KiB per row ----
#pragma unroll 2
  for (int i = 0; i < 16; i++) {
    const int row = (w << 4) | i;
    const int idx = fidx[row];
    const float4 v = *(const float4*)(emb + ((size_t)(h * K) + idx) * DH + l * 4);
    *(float4*)(outq + (size_t)(bbase + row) * (H * DH) + h * DH + l * 4) = v;
  }
}

// combined = ((idx0*512 + idx1)*512 + idx2)*512 + idx3 with int32 wraparound.
__global__ __launch_bounds__(256) void vq_combined(const int* __restrict__ idx_ws,
                                                   float* __restrict__ out_comb) {
  const int b = blockIdx.x * 256 + threadIdx.x;
  if (b < BT) {
    const int* p = idx_ws + (size_t)b * H;
    uint32_t cv = (uint32_t)p[0];
    cv = cv * 512u + (uint32_t)p[1];
    cv = cv * 512u + (uint32_t)p[2];
    cv = cv * 512u + (uint32_t)p[3];
    out_comb[b] = (float)(int32_t)cv;
  }
}

__global__ __launch_bounds__(256) void vq_perp(const float* __restrict__ avgp,
                                               float* __restrict__ out_perp) {
  const int t = threadIdx.x;
  float sh[H] = {0.f, 0.f, 0.f, 0.f};
  for (int i = t; i < H * K; i += 256) {
    const int h = i >> 9;
    float a = 0.0f;
#pragma unroll
    for (int c = 0; c < NREP; c++) a += avgp[c * (H * K) + i];
    a /= 65536.0f;
    sh[h] += a * logf(a + EPSL);
  }
  __shared__ float red[4][H];
#pragma unroll
  for (int h = 0; h < H; h++) {
    float s = sh[h];
#pragma unroll
    for (int m = 1; m < 64; m <<= 1) s += __shfl_xor(s, m);
    if ((t & 63) == 0) red[t >> 6][h] = s;
  }
  __syncthreads();
  if (t == 0) {
    float p = 0.0f;
#pragma unroll
    for (int h = 0; h < H; h++) {
      const float s = red[0][h] + red[1][h] + red[2][h] + red[3][h];
      p += expf(-s);
    }
    out_perp[0] = p * 0.25f;
  }
}

extern "C" void kernel_launch(void* const* d_in, const int* in_sizes, int n_in,
                              void* d_out, int out_size, void* d_ws, size_t ws_size,
                              hipStream_t stream) {
  const float* z_e    = (const float*)d_in[0];
  const float* emb    = (const float*)d_in[1];
  const float* scales = (const float*)d_in[2];
  float* out = (float*)d_out;

  float*          en_f   = (float*)d_ws;                        // 524288 floats
  unsigned short* en_b   = (unsigned short*)(en_f + (size_t)H * K * DH);
  float*          avgp   = (float*)(en_b + (size_t)H * K * DH); // NREP*2048 floats
  int*            idx_ws = (int*)(avgp + NREP * H * K);         // 262144 ints

  hipLaunchKernelGGL(vq_prep, dim3(H * K), dim3(256), 0, stream,
                     emb, en_f, en_b, avgp);
  hipLaunchKernelGGL(vq_main, dim3(BT / 64, H), dim3(256), 0, stream,
                     z_e, emb, scales, en_f, en_b, avgp, idx_ws, out);
  hipLaunchKernelGGL(vq_combined, dim3(BT / 256), dim3(256), 0, stream,
                     idx_ws, out + (size_t)BT * H * DH);
  hipLaunchKernelGGL(vq_perp, dim3(1), dim3(256), 0, stream,
                     avgp, out + (size_t)BT * H * DH + BT);
}

// Round 5
// 335.937 us; speedup vs baseline: 3.4797x; 1.0695x over previous
//
#include <hip/hip_runtime.h>
#include <stdint.h>
#include <math.h>

#define BT   65536
#define H    4
#define K    512
#define DH   256
#define EPSN 1e-12f
#define EPSL 1e-10f
#define TAU  0.03f
#define CTH  0.970446f      // exp(-TAU)
#define CMAX 16
#define NREP 8              // avg_probs accumulator replicas

typedef short bf16x8 __attribute__((ext_vector_type(8)));
typedef float f32x4  __attribute__((ext_vector_type(4)));

__device__ inline unsigned short f2bf(float f) {
  uint32_t u = __builtin_bit_cast(uint32_t, f);
  u += 0x7fffu + ((u >> 16) & 1u);
  return (unsigned short)(u >> 16);
}

// ---------------------------------------------------------------------------
// ws layout (float slots):
//   en_f  : [H][K][DH] fp32 normalized      524288 floats
//   en_b  : [H][K][DH] bf16 normalized      131072 float slots
//   avgp  : [NREP][H*K]                     16384 floats
//   idx_ws: [BT][H] int                     262144
// ---------------------------------------------------------------------------

__global__ __launch_bounds__(256) void vq_prep(const float* __restrict__ emb,
                                               float* __restrict__ en_f,
                                               unsigned short* __restrict__ en_b,
                                               float* __restrict__ avgp) {
  const int hk = blockIdx.x;        // h*K + k
  const int t  = threadIdx.x;       // d
  const float v = emb[(size_t)hk * DH + t];
  float s = v * v;
#pragma unroll
  for (int m = 1; m < 64; m <<= 1) s += __shfl_xor(s, m);
  __shared__ float wsum[4];
  if ((t & 63) == 0) wsum[t >> 6] = s;
  __syncthreads();
  const float tot = wsum[0] + wsum[1] + wsum[2] + wsum[3];
  const float n   = fmaxf(sqrtf(tot), EPSN);
  const float vn  = v / n;
  en_f[(size_t)hk * DH + t] = vn;
  en_b[(size_t)hk * DH + t] = f2bf(vn);
  if (t < NREP) avgp[t * (H * K) + hk] = 0.0f;
}

// Block: 64 b-rows x 512 codes for one h. 512 threads = 8 waves.
// SWAPPED MFMA: A = codes (en, from L2), B = z-rows (LDS). Wave w owns codes
// [64w, 64w+64): acc[4][4] = 64 f32/lane -> unified regs ~110 -> 4 waves/SIMD.
// C layout: code = 64w + 16mi + 4kg + q ; zrow = 16ni + arow.
__global__ __launch_bounds__(512, 4) void vq_main(
    const float* __restrict__ z_e, const float* __restrict__ emb,
    const float* __restrict__ scales,
    const float* __restrict__ en_f, const unsigned short* __restrict__ en_b,
    float* __restrict__ avgp, int* __restrict__ idx_ws,
    float* __restrict__ outq) {
  const int h     = blockIdx.y;
  const int bbase = blockIdx.x * 64;
  const int t     = threadIdx.x;
  const int w     = t >> 6;
  const int l     = t & 63;
  const int arow  = l & 15;
  const int kg    = l >> 4;                      // 0..3

  __shared__ unsigned short a_lds[64 * 256];     // 32 KiB z bf16, XOR-swizzled
  __shared__ float norms[64];
  __shared__ float wredm[8][64];                 // per-wave exp-maxes
  __shared__ float wreds[8][64];                 // per-wave exp-sums
  __shared__ int   wcols[8][64];
  __shared__ unsigned short cand[64][CMAX];
  __shared__ float gmx[64];
  __shared__ int   gcol[64];
  __shared__ float Srec[64];
  __shared__ int   cnt[64];
  __shared__ int   fidx[64];
  // LDS ~= 42.5 KiB -> 2 blocks/CU (85 KiB of 160)

  // ---- stage: load z row (8 lanes/row), L2-normalize (ref), bf16 -> LDS ----
  {
    const int row = t >> 3;                      // 0..63
    const int c8  = t & 7;
    const float* zp = z_e + (size_t)(bbase + row) * (H * DH) + h * DH;
    float4 q[8];
    float ss = 0.0f;
#pragma unroll
    for (int j = 0; j < 8; j++) {
      q[j] = *(const float4*)(zp + c8 * 4 + j * 32);
      ss += q[j].x * q[j].x + q[j].y * q[j].y + q[j].z * q[j].z + q[j].w * q[j].w;
    }
    ss += __shfl_xor(ss, 1);
    ss += __shfl_xor(ss, 2);
    ss += __shfl_xor(ss, 4);
    const float n   = fmaxf(sqrtf(ss), EPSN);
    const float inv = 1.0f / n;
    if (c8 == 0) norms[row] = n;
    const int swz = (row & 7) << 4;
#pragma unroll
    for (int j = 0; j < 8; j++) {
      const int d = c8 * 4 + j * 32;
      uint2 pk;
      pk.x = (uint32_t)f2bf(q[j].x * inv) | ((uint32_t)f2bf(q[j].y * inv) << 16);
      pk.y = (uint32_t)f2bf(q[j].z * inv) | ((uint32_t)f2bf(q[j].w * inv) << 16);
      *(uint2*)((char*)a_lds + row * 512 + ((d * 2) ^ swz)) = pk;
    }
    if (t < 64) cnt[t] = 0;
  }
  __syncthreads();

  // ---- MFMA GEMM: acc[mi][ni], A = en codes, B = z rows ----
  f32x4 acc[4][4];
#pragma unroll
  for (int mi = 0; mi < 4; mi++)
#pragma unroll
    for (int ni = 0; ni < 4; ni++) acc[mi][ni] = (f32x4){0.f, 0.f, 0.f, 0.f};

  const unsigned short* ep =
      en_b + ((size_t)(h * K) + w * 64 + arow) * DH + kg * 8;

#pragma unroll
  for (int ks = 0; ks < 8; ks++) {
    bf16x8 ef[4];
#pragma unroll
    for (int mi = 0; mi < 4; mi++)
      ef[mi] = *(const bf16x8*)(ep + (size_t)mi * 16 * DH + ks * 32);
    bf16x8 zf[4];
#pragma unroll
    for (int ni = 0; ni < 4; ni++) {
      const int rr = ni * 16 + arow;
      const int kb = (ks * 64) | (kg * 16);
      zf[ni] = *(const bf16x8*)((const char*)a_lds + rr * 512 +
                                (kb ^ ((rr & 7) << 4)));
    }
#pragma unroll
    for (int mi = 0; mi < 4; mi++)
#pragma unroll
      for (int ni = 0; ni < 4; ni++)
        acc[mi][ni] = __builtin_amdgcn_mfma_f32_16x16x32_bf16(ef[mi], zf[ni],
                                                              acc[mi][ni], 0, 0, 0);
  }

  // ---- pass 1: e = exp(sc*logit) in place; per-lane (4 rows) max/arg/sum ----
  const float sc = scales[h];
  float em[4]; int ec[4]; float es[4];
#pragma unroll
  for (int ni = 0; ni < 4; ni++) { em[ni] = 0.0f; ec[ni] = 1 << 30; es[ni] = 0.0f; }
#pragma unroll
  for (int mi = 0; mi < 4; mi++)
#pragma unroll
    for (int ni = 0; ni < 4; ni++)
#pragma unroll
      for (int q = 0; q < 4; q++) {
        const float e = __expf(sc * acc[mi][ni][q]);
        acc[mi][ni][q] = e;
        const int code = w * 64 + mi * 16 + kg * 4 + q;
        if (e > em[ni]) { em[ni] = e; ec[ni] = code; }
        es[ni] += e;
      }
  // combine over kg (same zrow, disjoint code subsets): masks 16, 32
#pragma unroll
  for (int m = 16; m < 64; m <<= 1) {
#pragma unroll
    for (int ni = 0; ni < 4; ni++) {
      const float om = __shfl_xor(em[ni], m);
      const int   oc = __shfl_xor(ec[ni], m);
      if (om > em[ni] || (om == em[ni] && oc < ec[ni])) { em[ni] = om; ec[ni] = oc; }
      es[ni] += __shfl_xor(es[ni], m);
    }
  }
  if (kg == 0) {
#pragma unroll
    for (int ni = 0; ni < 4; ni++) {
      const int r = ni * 16 + arow;
      wredm[w][r] = em[ni];
      wcols[w][r] = ec[ni];
      wreds[w][r] = es[ni];
    }
  }
  __syncthreads();
  if (t < 64) {
    float m = 0.0f; int c = 1 << 30; float s = 0.0f;
#pragma unroll
    for (int ww = 0; ww < 8; ww++) {
      const float vm = wredm[ww][t];
      const int   vc = wcols[ww][t];
      if (vm > m || (vm == m && vc < c)) { m = vm; c = vc; }
      s += wreds[ww][t];
    }
    gmx[t] = m; gcol[t] = c; Srec[t] = 1.0f / s;
  }
  __syncthreads();

  // ---- pass 2: candidate scan (e >= gmax*exp(-TAU)) + avg_probs ----
  {
    float rs[4], th[4];
#pragma unroll
    for (int ni = 0; ni < 4; ni++) {
      const int r = ni * 16 + arow;
      rs[ni] = Srec[r];
      th[ni] = gmx[r] * CTH;
    }
    float* ap = avgp + (blockIdx.x & (NREP - 1)) * (H * K) + h * K;
#pragma unroll
    for (int mi = 0; mi < 4; mi++)
#pragma unroll
      for (int q = 0; q < 4; q++) {
        float vs = 0.0f;
#pragma unroll
        for (int ni = 0; ni < 4; ni++) {
          const float e = acc[mi][ni][q];
          vs = fmaf(e, rs[ni], vs);
          if (e >= th[ni]) {
            const int r = ni * 16 + arow;
            const int p = atomicAdd(&cnt[r], 1);
            if (p < CMAX)
              cand[r][p] = (unsigned short)(w * 64 + mi * 16 + kg * 4 + q);
          }
        }
        vs += __shfl_xor(vs, 1);
        vs += __shfl_xor(vs, 2);
        vs += __shfl_xor(vs, 4);
        vs += __shfl_xor(vs, 8);
        if (arow == 0)
          atomicAdd(&ap[w * 64 + mi * 16 + kg * 4 + q], vs);
      }
  }
  __syncthreads();

  // ---- refine: exact fp32 dot for multi-candidate rows (64-lane coop) ----
  for (int i = 0; i < 8; i++) {
    const int r = w * 8 + i;
    int c = cnt[r];
    int best;
    if (c <= 1) {
      best = gcol[r];
    } else {
      if (c > CMAX) c = CMAX;
      const float nrm = norms[r];
      const float4 zq = *(const float4*)(z_e + (size_t)(bbase + r) * (H * DH) +
                                         h * DH + l * 4);
      const float zn0 = zq.x / nrm, zn1 = zq.y / nrm,
                  zn2 = zq.z / nrm, zn3 = zq.w / nrm;
      float bv = -INFINITY; int bi = 1 << 30;
      for (int i2 = 0; i2 < c; i2++) {
        const int cc = cand[r][i2];
        const float4 eq = *(const float4*)(en_f + ((size_t)(h * K) + cc) * DH + l * 4);
        float d0 = fmaf(zn0, eq.x, fmaf(zn1, eq.y, fmaf(zn2, eq.z, zn3 * eq.w)));
#pragma unroll
        for (int m = 1; m < 64; m <<= 1) d0 += __shfl_xor(d0, m);
        if (d0 > bv || (d0 == bv && cc < bi)) { bv = d0; bi = cc; }
      }
      best = bi;
    }
    if (l == 0) fidx[r] = best;
  }
  __syncthreads();

  if (t < 64) idx_ws[(size_t)(bbase + t) * H + h] = fidx[t];

  // ---- fused z_q gather: raw emb rows, coalesced 1 KiB per row ----
#pragma unroll 2
  for (int i = 0; i < 8; i++) {
    const int row = w * 8 + i;
    const int idx = fidx[row];
    const float4 v = *(const float4*)(emb + ((size_t)(h * K) + idx) * DH + l * 4);
    *(float4*)(outq + (size_t)(bbase + row) * (H * DH) + h * DH + l * 4) = v;
  }
}

// combined = ((idx0*512 + idx1)*512 + idx2)*512 + idx3 with int32 wraparound.
__global__ __launch_bounds__(256) void vq_combined(const int* __restrict__ idx_ws,
                                                   float* __restrict__ out_comb) {
  const int b = blockIdx.x * 256 + threadIdx.x;
  if (b < BT) {
    const int* p = idx_ws + (size_t)b * H;
    uint32_t cv = (uint32_t)p[0];
    cv = cv * 512u + (uint32_t)p[1];
    cv = cv * 512u + (uint32_t)p[2];
    cv = cv * 512u + (uint32_t)p[3];
    out_comb[b] = (float)(int32_t)cv;
  }
}

__global__ __launch_bounds__(256) void vq_perp(const float* __restrict__ avgp,
                                               float* __restrict__ out_perp) {
  const int t = threadIdx.x;
  float sh[H] = {0.f, 0.f, 0.f, 0.f};
  for (int i = t; i < H * K; i += 256) {
    const int h = i >> 9;
    float a = 0.0f;
#pragma unroll
    for (int c = 0; c < NREP; c++) a += avgp[c * (H * K) + i];
    a /= 65536.0f;
    sh[h] += a * logf(a + EPSL);
  }
  __shared__ float red[4][H];
#pragma unroll
  for (int h = 0; h < H; h++) {
    float s = sh[h];
#pragma unroll
    for (int m = 1; m < 64; m <<= 1) s += __shfl_xor(s, m);
    if ((t & 63) == 0) red[t >> 6][h] = s;
  }
  __syncthreads();
  if (t == 0) {
    float p = 0.0f;
#pragma unroll
    for (int h = 0; h < H; h++) {
      const float s = red[0][h] + red[1][h] + red[2][h] + red[3][h];
      p += expf(-s);
    }
    out_perp[0] = p * 0.25f;
  }
}

extern "C" void kernel_launch(void* const* d_in, const int* in_sizes, int n_in,
                              void* d_out, int out_size, void* d_ws, size_t ws_size,
                              hipStream_t stream) {
  const float* z_e    = (const float*)d_in[0];
  const float* emb    = (const float*)d_in[1];
  const float* scales = (const float*)d_in[2];
  float* out = (float*)d_out;

  float*          en_f   = (float*)d_ws;                        // 524288 floats
  unsigned short* en_b   = (unsigned short*)(en_f + (size_t)H * K * DH);
  float*          avgp   = (float*)(en_b + (size_t)H * K * DH); // NREP*2048 floats
  int*            idx_ws = (int*)(avgp + NREP * H * K);         // 262144 ints

  hipLaunchKernelGGL(vq_prep, dim3(H * K), dim3(256), 0, stream,
                     emb, en_f, en_b, avgp);
  hipLaunchKernelGGL(vq_main, dim3(BT / 64, H), dim3(512), 0, stream,
                     z_e, emb, scales, en_f, en_b, avgp, idx_ws, out);
  hipLaunchKernelGGL(vq_combined, dim3(BT / 256), dim3(256), 0, stream,
                     idx_ws, out + (size_t)BT * H * DH);
  hipLaunchKernelGGL(vq_perp, dim3(1), dim3(256), 0, stream,
                     avgp, out + (size_t)BT * H * DH + BT);
}